// Round 2
// baseline (36.884 us; speedup 1.0000x reference)
//
#include <hip/hip_runtime.h>

// AnchorProcessor: x[8,255,128,128] f32 -> out[8,18,128,128] f32
// float4 everywhere (16 B/lane). Block=256: chalf=tid>>7 (class half, wave-uniform),
// n=(tid>>4)&7, p=tid&15 (16 lanes x 4 pixels = 64 pixels/block). Grid=256 blocks.
// Cross-(n,chalf) max/argmax combine in LDS with flat-index (n*80+c) tie-break.

#define NN   8
#define AA   3
#define CLSN 80
#define HW   16384           // 128*128
#define CH   255             // 3*85

__device__ __forceinline__ float sigf(float v) {
    return 1.0f / (1.0f + __expf(-v));
}

__global__ __launch_bounds__(256)
void anchor_kernel_v2(const float* __restrict__ x, float* __restrict__ out) {
    const int tid   = threadIdx.x;
    const int p     = tid & 15;          // lane group: 16 lanes x float4
    const int n     = (tid >> 4) & 7;
    const int chalf = tid >> 7;          // 0: classes 0..39 (+boxes), 1: classes 40..79
    const int pix   = blockIdx.x * 64 + p * 4;   // flat pixel, float4-aligned
    const int h     = pix >> 7;
    const int w0    = pix & 127;

    const float anchw[AA] = {116.f, 156.f, 373.f};
    const float anchh[AA] = { 90.f, 198.f, 326.f};

    const int nbase = n * (CH * HW) + pix;

    __shared__ float4 s_val[AA][NN][2][16];
    __shared__ int4   s_idx[AA][NN][2][16];

    #pragma unroll
    for (int a = 0; a < AA; ++a) {
        const int abase = nbase + (a * 85) * HW;
        const float4 obj = *(const float4*)(x + abase + 4 * HW);

        if (chalf == 0) {   // wave-uniform branch
            const float4 tx = *(const float4*)(x + abase + 0 * HW);
            const float4 ty = *(const float4*)(x + abase + 1 * HW);
            const float4 tw = *(const float4*)(x + abase + 2 * HW);
            const float4 th = *(const float4*)(x + abase + 3 * HW);
            float4 bx, by, bw, bh;
            bx.x = sigf(tx.x) + (float)(w0 + 0);
            bx.y = sigf(tx.y) + (float)(w0 + 1);
            bx.z = sigf(tx.z) + (float)(w0 + 2);
            bx.w = sigf(tx.w) + (float)(w0 + 3);
            const float fh = (float)h;
            by.x = sigf(ty.x) + fh;  by.y = sigf(ty.y) + fh;
            by.z = sigf(ty.z) + fh;  by.w = sigf(ty.w) + fh;
            bw.x = tw.x * anchw[a];  bw.y = tw.y * anchw[a];
            bw.z = tw.z * anchw[a];  bw.w = tw.w * anchw[a];
            bh.x = th.x * anchh[a];  bh.y = th.y * anchh[a];
            bh.z = th.z * anchh[a];  bh.w = th.w * anchh[a];
            const int obase = (n * 18 + a * 6) * HW + pix;
            *(float4*)(out + obase + 0 * HW) = bx;
            *(float4*)(out + obase + 1 * HW) = by;
            *(float4*)(out + obase + 2 * HW) = bw;
            *(float4*)(out + obase + 3 * HW) = bh;
        }

        // 40-class partial reduction (flat idx = n*80 + chalf*40 + c, first-max)
        float4 best = make_float4(-__builtin_inff(), -__builtin_inff(),
                                  -__builtin_inff(), -__builtin_inff());
        int4 bidx = make_int4(0x7fffffff, 0x7fffffff, 0x7fffffff, 0x7fffffff);
        const int cbeg = 5 + chalf * 40;
        const int ibeg = n * CLSN + chalf * 40;
        #pragma unroll 8
        for (int c = 0; c < 40; ++c) {
            float4 v = *(const float4*)(x + abase + (cbeg + c) * HW);
            v.x *= obj.x; v.y *= obj.y; v.z *= obj.z; v.w *= obj.w;
            const int id = ibeg + c;
            if (v.x > best.x) { best.x = v.x; bidx.x = id; }
            if (v.y > best.y) { best.y = v.y; bidx.y = id; }
            if (v.z > best.z) { best.z = v.z; bidx.z = id; }
            if (v.w > best.w) { best.w = v.w; bidx.w = id; }
        }
        s_val[a][n][chalf][p] = best;
        s_idx[a][n][chalf][p] = bidx;
    }
    __syncthreads();

    // combine the 16 partials per (a, pixel4); result identical for all threads
    // with the same p. chalf=0 writes smax (its n), chalf=1 writes sarg (its n).
    #pragma unroll
    for (int a = 0; a < AA; ++a) {
        float4 best = make_float4(-__builtin_inff(), -__builtin_inff(),
                                  -__builtin_inff(), -__builtin_inff());
        int4 bidx = make_int4(0x7fffffff, 0x7fffffff, 0x7fffffff, 0x7fffffff);
        #pragma unroll
        for (int nn = 0; nn < NN; ++nn) {
            #pragma unroll
            for (int ch = 0; ch < 2; ++ch) {
                const float4 v  = s_val[a][nn][ch][p];
                const int4   id = s_idx[a][nn][ch][p];
                if (v.x > best.x || (v.x == best.x && id.x < bidx.x)) { best.x = v.x; bidx.x = id.x; }
                if (v.y > best.y || (v.y == best.y && id.y < bidx.y)) { best.y = v.y; bidx.y = id.y; }
                if (v.z > best.z || (v.z == best.z && id.z < bidx.z)) { best.z = v.z; bidx.z = id.z; }
                if (v.w > best.w || (v.w == best.w && id.w < bidx.w)) { best.w = v.w; bidx.w = id.w; }
            }
        }
        const int obase = (n * 18 + a * 6) * HW + pix;
        if (chalf == 0) {
            *(float4*)(out + obase + 4 * HW) = best;
        } else {
            float4 f;
            f.x = (float)bidx.x; f.y = (float)bidx.y;
            f.z = (float)bidx.z; f.w = (float)bidx.w;
            *(float4*)(out + obase + 5 * HW) = f;
        }
    }
}

extern "C" void kernel_launch(void* const* d_in, const int* in_sizes, int n_in,
                              void* d_out, int out_size, void* d_ws, size_t ws_size,
                              hipStream_t stream) {
    const float* x = (const float*)d_in[0];
    float* out = (float*)d_out;
    dim3 grid(HW / 64);   // 256 blocks, 64 pixels each
    dim3 block(256);
    hipLaunchKernelGGL(anchor_kernel_v2, grid, block, 0, stream, x, out);
}